// Round 1
// baseline (670.269 us; speedup 1.0000x reference)
//
#include <hip/hip_runtime.h>

// Problem constants (from reference setup_inputs)
#define N_NODES 12288
#define N_EDGES 393216
#define LATENT  128

// Edge index needs 19 bits (393216 <= 2^19), key = r*N+c needs 28 bits (< 2^28).
#define E_BITS  19
#define E_MASK  ((1u << E_BITS) - 1u)

__device__ __forceinline__ unsigned int hash32(unsigned int key) {
    key ^= key >> 16; key *= 0x85ebca6bu;
    key ^= key >> 13; key *= 0xc2b2ae35u;
    key ^= key >> 16;
    return key;
}

// s1[n] = dot(z[n], W[0:128]), s2[n] = dot(z[n], W[128:256]). One wave per node.
__global__ void node_dots(const float* __restrict__ z, const float* __restrict__ W,
                          float* __restrict__ s1, float* __restrict__ s2) {
    int node = (int)((blockIdx.x * blockDim.x + threadIdx.x) >> 6);
    int lane = (int)(threadIdx.x & 63);
    if (node >= N_NODES) return;
    const float* zr = z + (size_t)node * LATENT;
    float a  = zr[lane];
    float bb = zr[lane + 64];
    float p1 = a * W[lane]       + bb * W[lane + 64];
    float p2 = a * W[lane + 128] + bb * W[lane + 192];
    #pragma unroll
    for (int off = 32; off > 0; off >>= 1) {
        p1 += __shfl_down(p1, off, 64);
        p2 += __shfl_down(p2, off, 64);
    }
    if (lane == 0) { s1[node] = p1; s2[node] = p2; }
}

// Pass 1: build open-addressed hash table mapping key -> max edge index (last-write-wins).
// Entry layout: [(key+1) << 19] | e ; 0 = empty. Same-key entries compare by e under max.
__global__ void build_table(const int* __restrict__ ei,
                            unsigned long long* __restrict__ table,
                            unsigned int tab_mask) {
    int e = (int)(blockIdx.x * blockDim.x + threadIdx.x);
    if (e >= N_EDGES) return;
    unsigned int r = (unsigned int)ei[e];
    unsigned int c = (unsigned int)ei[e + N_EDGES];
    unsigned int key = r * (unsigned int)N_NODES + c;
    unsigned long long packed = (((unsigned long long)(key + 1u)) << E_BITS) | (unsigned int)e;
    unsigned int h = hash32(key) & tab_mask;
    for (;;) {
        unsigned long long old = atomicCAS(&table[h], 0ull, packed);
        if (old == 0ull) break;                        // claimed empty slot
        if ((unsigned int)(old >> E_BITS) == key + 1u) {
            atomicMax(&table[h], packed);              // same key: keep max edge idx
            break;
        }
        h = (h + 1u) & tab_mask;                       // different key: linear probe
    }
}

// Pass 2: every edge atomicAdds its attr sum; the winning (last) edge per cell
// additionally adds s1[r] + s2[c] + b.
__global__ void scatter_edges(const int* __restrict__ ei, const float* __restrict__ ea,
                              const float* __restrict__ s1, const float* __restrict__ s2,
                              const float* __restrict__ bptr,
                              const unsigned long long* __restrict__ table,
                              unsigned int tab_mask,
                              float* __restrict__ out) {
    int e = (int)(blockIdx.x * blockDim.x + threadIdx.x);
    if (e >= N_EDGES) return;
    unsigned int r = (unsigned int)ei[e];
    unsigned int c = (unsigned int)ei[e + N_EDGES];
    unsigned int key = r * (unsigned int)N_NODES + c;
    float4 a4 = ((const float4*)ea)[e];
    float val = a4.x + a4.y + a4.z + a4.w;

    unsigned int h = hash32(key) & tab_mask;
    for (;;) {
        unsigned long long entry = table[h];
        if (entry == 0ull) break;                      // defensive: cannot happen
        if ((unsigned int)(entry >> E_BITS) == key + 1u) {
            if ((unsigned int)(entry & E_MASK) == (unsigned int)e)
                val += s1[r] + s2[c] + bptr[0];
            break;
        }
        h = (h + 1u) & tab_mask;
    }
    atomicAdd(&out[(size_t)key], val);
}

extern "C" void kernel_launch(void* const* d_in, const int* in_sizes, int n_in,
                              void* d_out, int out_size, void* d_ws, size_t ws_size,
                              hipStream_t stream) {
    const float* z  = (const float*)d_in[0];
    const int*   ei = (const int*)d_in[1];    // [2, E] as int32
    const float* ea = (const float*)d_in[2];  // [E, 4]
    const float* W  = (const float*)d_in[3];  // [256]
    const float* b  = (const float*)d_in[4];  // [1]
    float* out = (float*)d_out;

    // Workspace layout: s1 (N floats) | s2 (N floats) | hash table (2^bits u64)
    char* ws = (char*)d_ws;
    float* s1 = (float*)ws;
    float* s2 = (float*)(ws + (size_t)N_NODES * sizeof(float));
    unsigned long long* table = (unsigned long long*)(ws + 2ull * N_NODES * sizeof(float));
    size_t head = 2ull * N_NODES * sizeof(float);

    // Pick the largest table that fits (19..22 bits); 19 bits (0.75 load) is the floor.
    int bits = 19;
    while (bits < 22 && head + (8ull << (bits + 1)) <= ws_size) bits++;
    unsigned int tab_mask = (1u << bits) - 1u;
    size_t tab_bytes = 8ull << bits;

    // Zero the dense output (604 MB) and the hash table (ws is poisoned each call).
    hipMemsetAsync(d_out, 0, (size_t)out_size * sizeof(float), stream);
    hipMemsetAsync(table, 0, tab_bytes, stream);

    node_dots<<<N_NODES / 4, 256, 0, stream>>>(z, W, s1, s2);
    build_table<<<N_EDGES / 256, 256, 0, stream>>>(ei, table, tab_mask);
    scatter_edges<<<N_EDGES / 256, 256, 0, stream>>>(ei, ea, s1, s2, b, table, tab_mask, out);
}